// Round 4
// baseline (536.564 us; speedup 1.0000x reference)
//
#include <hip/hip_runtime.h>
#include <cmath>

#define NB 16
#define NL 64
#define NP 512
#define NH 128
#define NG 10
#define ROWS (NB * NL * NP)          // 524288 rows

// output layout (flat float32, reference return order)
#define OFF_PI    ((size_t)0)
#define OFF_SIGMA ((size_t)5242880)
#define OFF_MU    ((size_t)10485760)
#define OFF_DIST  ((size_t)15728640)
#define OFF_MASK  ((size_t)16252928)

// ---------------------------------------------------------------------------
// Fused kernel: min-dist over 24 atoms + 3x GEMV [128 -> 10] + activations.
// One thread per (b, l, p) == one row of Interact. 256 rows per block.
//
// R4: X staged via __builtin_amdgcn_global_load_lds (16B) -- no VGPR
// round-trip (R2/R3's pf[8] cross-barrier buffer was being spilled to
// scratch: ~512 B/thread of spill writes == the measured 250 MB excess
// WRITE_SIZE). LDS dest is linear (gll requirement); bank conflicts on the
// read side are avoided by XOR-swizzling the per-lane GLOBAL source:
//   LDS slot (row r, chunk c) holds global chunk c^(r&7) of row r.
//   Reader (thread r) fetches chunk j from slot j^(r&7):
//     byte = 128*r + 16*(j^(r&7)) -> 8 lanes per 4-bank quad, all 32 banks
//     evenly loaded = optimal ds_read_b128.
// The XOR permutes 16B chunks within one 128B-aligned line -> global
// coalescing unchanged (8 full lines per gll instruction).
// ---------------------------------------------------------------------------
__global__ __launch_bounds__(256, 4) void k_fused(
    const float* __restrict__ pos_l,   // [B, NL, 3]
    const float* __restrict__ pos_p,   // [B, NP, 24, 3]
    const int*   __restrict__ mask,    // [B, NL, NP] (bool as int32)
    const float* __restrict__ X,       // [ROWS, 128]
    const float* __restrict__ Wpi, const float* __restrict__ bpi,
    const float* __restrict__ Wsg, const float* __restrict__ bsg,
    const float* __restrict__ Wmu, const float* __restrict__ bmu,
    float* __restrict__ out_pi,
    float* __restrict__ out_sg,
    float* __restrict__ out_mu,
    float* __restrict__ dist_out,
    float* __restrict__ mask_out)
{
    __shared__ __align__(16) float xs[256 * 32];   // 32 KB, linear layout

    const int tid  = threadIdx.x;
    const int lane = tid & 63;
    const int wv   = tid >> 6;                     // wave id 0..3
    const int idx  = blockIdx.x * 256 + tid;       // b*NL*NP + l*NP + p
    const size_t row0 = (size_t)blockIdx.x * 256;

    // gll inst (wv, j): lane l writes float4-slot S = j*256 + wv*64 + l
    //   -> row r = 32j + 8wv + (l>>3), chunk c = l&7.
    // Source must be global chunk c ^ (r&7) = (l&7) ^ (l>>3).
    const int rsub = lane >> 3;                    // 0..7
    const int csw  = (lane & 7) ^ rsub;            // swizzled source chunk
    const float* gs = X + (row0 + 8 * wv + rsub) * NH + 4 * csw;
    char* lb = (char*)xs + 1024 * wv;              // wave-uniform LDS base

    // ---- issue stage 0 (async; lands while dist part computes) ----
    #pragma unroll
    for (int j = 0; j < 8; ++j)                    // j step: 32 rows
        __builtin_amdgcn_global_load_lds(
            (const __attribute__((address_space(1))) void*)(gs + 4096 * j),
            (__attribute__((address_space(3))) void*)(lb + 4096 * j),
            16, 0, 0);

    // ---------------- distance part ----------------
    float dist_v, mask_v;
    {
        int p  = idx & (NP - 1);
        int bl = idx >> 9;                      // b*NL + l
        int b  = bl >> 6;

        const float* xl = pos_l + bl * 3;
        float x0 = xl[0], x1 = xl[1], x2 = xl[2];
        float qs = x0 * x0 + x1 * x1 + x2 * x2;

        // 24 atoms * 3 floats = 18 float4 per residue (288B rows, 16B aligned)
        const float4* yp = (const float4*)(pos_p + ((size_t)(b * NP + p)) * 72);

        // d2<0 -> NaN -> 10000 in the reference: clamp to 1e8 (=10000^2
        // exactly) and take one sqrt of the min at the end.
        float m2 = 1e30f;
        #pragma unroll
        for (int q = 0; q < 6; ++q) {           // 4 atoms per iteration
            float4 v0 = yp[q * 3 + 0];
            float4 v1 = yp[q * 3 + 1];
            float4 v2 = yp[q * 3 + 2];
            float c[12] = {v0.x, v0.y, v0.z, v0.w,
                           v1.x, v1.y, v1.z, v1.w,
                           v2.x, v2.y, v2.z, v2.w};
            #pragma unroll
            for (int a = 0; a < 4; ++a) {
                float yx = c[a * 3 + 0], yy = c[a * 3 + 1], yz = c[a * 3 + 2];
                float d2 = qs + (yx * yx + yy * yy + yz * yz)
                              - 2.0f * (x0 * yx + x1 * yy + x2 * yz);
                d2 = (d2 >= 0.0f) ? d2 : 1e8f;
                m2 = fminf(m2, d2);
            }
        }
        float m = sqrtf(m2);

        int mk = mask[idx];
        dist_v = mk ? m : 0.0f;
        mask_v = mk ? 1.0f : 0.0f;
    }
    dist_out[idx] = dist_v;                     // dense 4B/lane stores
    mask_out[idx] = mask_v;

    // ---------------- GEMV part ----------------
    float accp[NG], accs[NG], accm[NG];
    #pragma unroll
    for (int g = 0; g < NG; ++g) {              // uniform-index -> s_load
        accp[g] = bpi[g];
        accs[g] = bsg[g];
        accm[g] = bmu[g];
    }

    const float4* xr4 = (const float4*)xs + tid * 8;   // row base (byte 128*tid)
    const int sw = tid & 7;

    for (int kc = 0; kc < 4; ++kc) {
        __syncthreads();                        // drains vmcnt(0): stage kc
                                                // landed in LDS + visible
        const float* wp0 = Wpi + kc * 32 * NG;  // wave-uniform -> s_load
        const float* ws0 = Wsg + kc * 32 * NG;
        const float* wm0 = Wmu + kc * 32 * NG;

        #pragma unroll
        for (int j = 0; j < 8; ++j) {
            float4 h4 = xr4[j ^ sw];            // conflict-free ds_read_b128
            float hk[4] = {h4.x, h4.y, h4.z, h4.w};
            #pragma unroll
            for (int kk = 0; kk < 4; ++kk) {
                const float* wp = wp0 + (j * 4 + kk) * NG;
                const float* ws = ws0 + (j * 4 + kk) * NG;
                const float* wm = wm0 + (j * 4 + kk) * NG;
                float h = hk[kk];
                #pragma unroll
                for (int g = 0; g < NG; ++g) {
                    accp[g] = fmaf(h, wp[g], accp[g]);
                    accs[g] = fmaf(h, ws[g], accs[g]);
                    accm[g] = fmaf(h, wm[g], accm[g]);
                }
            }
        }

        if (kc < 3) {
            __syncthreads();                    // all reads of xs done
            gs += 32;                           // next 32-float k-slice
            #pragma unroll
            for (int j = 0; j < 8; ++j)
                __builtin_amdgcn_global_load_lds(
                    (const __attribute__((address_space(1))) void*)(gs + 4096 * j),
                    (__attribute__((address_space(3))) void*)(lb + 4096 * j),
                    16, 0, 0);
        }
    }

    // ---------------- epilogue ----------------
    const size_t ro = (size_t)idx * NG;         // byte offset idx*40: 8-aligned

    // pi = softmax(accp)
    float mx = accp[0];
    #pragma unroll
    for (int g = 1; g < NG; ++g) mx = fmaxf(mx, accp[g]);
    float e[NG], ssum = 0.0f;
    #pragma unroll
    for (int g = 0; g < NG; ++g) { e[g] = __expf(accp[g] - mx); ssum += e[g]; }
    float inv = 1.0f / ssum;
    #pragma unroll
    for (int g = 0; g < 5; ++g)
        *(float2*)&out_pi[ro + 2 * g] = make_float2(e[2 * g] * inv,
                                                    e[2 * g + 1] * inv);

    // sigma = clip(leaky(accs) + 1.1, 1e-6, inf)
    #pragma unroll
    for (int g = 0; g < 5; ++g) {
        float xa = accs[2 * g], xb = accs[2 * g + 1];
        float va = fmaxf((xa >= 0.0f ? xa : 0.01f * xa) + 1.1f, 1e-6f);
        float vb = fmaxf((xb >= 0.0f ? xb : 0.01f * xb) + 1.1f, 1e-6f);
        *(float2*)&out_sg[ro + 2 * g] = make_float2(va, vb);
    }

    // mu = leaky(accm) + 1.0
    #pragma unroll
    for (int g = 0; g < 5; ++g) {
        float xa = accm[2 * g], xb = accm[2 * g + 1];
        float va = (xa >= 0.0f ? xa : 0.01f * xa) + 1.0f;
        float vb = (xb >= 0.0f ? xb : 0.01f * xb) + 1.0f;
        *(float2*)&out_mu[ro + 2 * g] = make_float2(va, vb);
    }
}

// ---------------------------------------------------------------------------
extern "C" void kernel_launch(void* const* d_in, const int* in_sizes, int n_in,
                              void* d_out, int out_size, void* d_ws, size_t ws_size,
                              hipStream_t stream) {
    const float* pos_l    = (const float*)d_in[0];
    const float* pos_p    = (const float*)d_in[1];
    const float* Interact = (const float*)d_in[2];
    const int*   mask     = (const int*)  d_in[3];
    const float* Wpi      = (const float*)d_in[4];
    const float* bpi      = (const float*)d_in[5];
    const float* Wsg      = (const float*)d_in[6];
    const float* bsg      = (const float*)d_in[7];
    const float* Wmu      = (const float*)d_in[8];
    const float* bmu      = (const float*)d_in[9];

    float* out      = (float*)d_out;
    float* out_pi   = out + OFF_PI;
    float* out_sg   = out + OFF_SIGMA;
    float* out_mu   = out + OFF_MU;
    float* out_dist = out + OFF_DIST;
    float* out_mask = out + OFF_MASK;

    hipLaunchKernelGGL(k_fused, dim3(ROWS / 256), dim3(256), 0, stream,
                       pos_l, pos_p, mask, Interact,
                       Wpi, bpi, Wsg, bsg, Wmu, bmu,
                       out_pi, out_sg, out_mu, out_dist, out_mask);
}

// Round 5
// 402.251 us; speedup vs baseline: 1.3339x; 1.3339x over previous
//
#include <hip/hip_runtime.h>
#include <cmath>

#define NB 16
#define NL 64
#define NP 512
#define NH 128
#define NG 10
#define ROWS (NB * NL * NP)          // 524288 rows

// output layout (flat float32, reference return order)
#define OFF_PI    ((size_t)0)
#define OFF_SIGMA ((size_t)5242880)
#define OFF_MU    ((size_t)10485760)
#define OFF_DIST  ((size_t)15728640)
#define OFF_MASK  ((size_t)16252928)

typedef __attribute__((ext_vector_type(8))) short short8;  // 8 bf16 = 4 VGPR
typedef __attribute__((ext_vector_type(4))) float f32x4;   // MFMA acc

// pack two f32 into one dword of two bf16 (round-nearest-even)
__device__ __forceinline__ unsigned pk2(float a, float b) {
    unsigned ua = __float_as_uint(a);
    unsigned ub = __float_as_uint(b);
    ua = (ua + 0x7fffu + ((ua >> 16) & 1u)) >> 16;
    ub = (ub + 0x7fffu + ((ub >> 16) & 1u)) & 0xffff0000u;
    return ua | ub;
}

// ---------------------------------------------------------------------------
// Fused kernel: min-dist over 24 atoms + 3x GEMV [128 -> 30] + activations.
//
// R5: GEMV via v_mfma_f32_16x16x32_bf16. Outputs packed as 32 cols
// [pi(10)|sg(10)|mu(10)|pad(2)]. Per wave: rows [64*wv,64*wv+64) of the
// block = 4 M-tiles x 2 N-tiles x 4 K-steps = 32 MFMAs (replaces 3840
// per-thread FMAs + the per-wave SMEM weight storm that made R1-R4
// issue-bound). X streams from global (no reuse -> no LDS staging, no
// barriers). A/B frags packed with the SAME assumed k-map, so the exact
// HW k-permutation cancels in the dot product. acc init = bias (f32
// exact). C/D layout (verified m89/m91): col=lane&15, row=(lane>>4)*4+reg.
// Epilogue: wave-private C->LDS (stride-36: write 2-way=free, read
// balanced b128), same-wave lgkmcnt ordering only, then thread-per-row
// activations + stores (proven in R2-R4).
// ---------------------------------------------------------------------------
__global__ __launch_bounds__(256, 3) void k_fused(
    const float* __restrict__ pos_l,   // [B, NL, 3]
    const float* __restrict__ pos_p,   // [B, NP, 24, 3]
    const int*   __restrict__ mask,    // [B, NL, NP] (bool as int32)
    const float* __restrict__ X,       // [ROWS, 128]
    const float* __restrict__ Wpi, const float* __restrict__ bpi,
    const float* __restrict__ Wsg, const float* __restrict__ bsg,
    const float* __restrict__ Wmu, const float* __restrict__ bmu,
    float* __restrict__ out_pi,
    float* __restrict__ out_sg,
    float* __restrict__ out_mu,
    float* __restrict__ dist_out,
    float* __restrict__ mask_out)
{
    // per-wave C regions: [4 waves][64 rows][36 cols] f32 = 36864 B
    __shared__ __align__(16) float cs[4 * 64 * 36];

    const int tid  = threadIdx.x;
    const int wv   = tid >> 6;
    const int lane = tid & 63;
    const int lrow = lane & 15;              // A-row / C-col within tile
    const int lkg  = lane >> 4;              // k-group
    const int idx  = blockIdx.x * 256 + tid; // b*NL*NP + l*NP + p
    const size_t row0 = (size_t)blockIdx.x * 256;

    // ---------------- distance part ----------------
    {
        int p  = idx & (NP - 1);
        int bl = idx >> 9;                   // b*NL + l
        int b  = bl >> 6;

        const float* xl = pos_l + bl * 3;
        float x0 = xl[0], x1 = xl[1], x2 = xl[2];
        float qs = x0 * x0 + x1 * x1 + x2 * x2;

        const float4* yp = (const float4*)(pos_p + ((size_t)(b * NP + p)) * 72);

        // d2<0 -> NaN -> 10000 in the ref: clamp to 1e8 (=10000^2 exactly),
        // one sqrt of the min at the end.
        float m2 = 1e30f;
        #pragma unroll
        for (int q = 0; q < 6; ++q) {
            float4 v0 = yp[q * 3 + 0];
            float4 v1 = yp[q * 3 + 1];
            float4 v2 = yp[q * 3 + 2];
            float c[12] = {v0.x, v0.y, v0.z, v0.w,
                           v1.x, v1.y, v1.z, v1.w,
                           v2.x, v2.y, v2.z, v2.w};
            #pragma unroll
            for (int a = 0; a < 4; ++a) {
                float yx = c[a * 3 + 0], yy = c[a * 3 + 1], yz = c[a * 3 + 2];
                float d2 = qs + (yx * yx + yy * yy + yz * yz)
                              - 2.0f * (x0 * yx + x1 * yy + x2 * yz);
                d2 = (d2 >= 0.0f) ? d2 : 1e8f;
                m2 = fminf(m2, d2);
            }
        }
        float m = sqrtf(m2);
        int mk = mask[idx];
        dist_out[idx] = mk ? m : 0.0f;
        mask_out[idx] = mk ? 1.0f : 0.0f;
    }

    // ---------------- per-lane column mapping (packed cols) ----------------
    // col c: 0-9 pi | 10-19 sigma | 20-29 mu | 30,31 pad
    const int c0 = lrow;                     // n-tile 0 col
    const int c1 = lrow + 16;                // n-tile 1 col
    const float* wb0; float bv0;
    if (c0 < 10) { wb0 = Wpi + c0;      bv0 = bpi[c0]; }
    else         { wb0 = Wsg + c0 - 10; bv0 = bsg[c0 - 10]; }
    const float* wb1; float bv1; bool pad1;
    if (c1 < 20)      { wb1 = Wsg + c1 - 10; bv1 = bsg[c1 - 10]; pad1 = false; }
    else if (c1 < 30) { wb1 = Wmu + c1 - 20; bv1 = bmu[c1 - 20]; pad1 = false; }
    else              { wb1 = Wpi;           bv1 = 0.0f;         pad1 = true; }

    // ---------------- MFMA GEMV ----------------
    f32x4 acc[4][2];
    #pragma unroll
    for (int m = 0; m < 4; ++m) {
        acc[m][0] = (f32x4){bv0, bv0, bv0, bv0};
        acc[m][1] = (f32x4){bv1, bv1, bv1, bv1};
    }

    const float* xbase = X + (row0 + wv * 64 + lrow) * NH + lkg * 8;

    #pragma unroll 1
    for (int ks = 0; ks < 4; ++ks) {
        const int kb = ks * 32 + lkg * 8;    // this lane's 8 consecutive k
        // B fragments (weights, L2-hot after first blocks)
        float w0[8], w1[8];
        #pragma unroll
        for (int j = 0; j < 8; ++j) {
            w0[j] = wb0[(kb + j) * NG];
            float t = wb1[(kb + j) * NG];
            w1[j] = pad1 ? 0.0f : t;
        }
        uint4 u0 = {pk2(w0[0], w0[1]), pk2(w0[2], w0[3]),
                    pk2(w0[4], w0[5]), pk2(w0[6], w0[7])};
        uint4 u1 = {pk2(w1[0], w1[1]), pk2(w1[2], w1[3]),
                    pk2(w1[4], w1[5]), pk2(w1[6], w1[7])};
        short8 bf0 = __builtin_bit_cast(short8, u0);
        short8 bf1 = __builtin_bit_cast(short8, u1);

        #pragma unroll
        for (int m = 0; m < 4; ++m) {
            const float* ap = xbase + (size_t)m * 16 * NH + ks * 32;
            float4 lo = *(const float4*)ap;        // 32B contiguous per lane
            float4 hi = *(const float4*)(ap + 4);
            uint4 ua = {pk2(lo.x, lo.y), pk2(lo.z, lo.w),
                        pk2(hi.x, hi.y), pk2(hi.z, hi.w)};
            short8 af = __builtin_bit_cast(short8, ua);
            acc[m][0] = __builtin_amdgcn_mfma_f32_16x16x32_bf16(af, bf0, acc[m][0], 0, 0, 0);
            acc[m][1] = __builtin_amdgcn_mfma_f32_16x16x32_bf16(af, bf1, acc[m][1], 0, 0, 0);
        }
    }

    // ---------------- C -> LDS (wave-private, no barrier needed) ----------
    // C/D: col = lane&15, row = (lane>>4)*4 + reg. Stride 36 floats:
    // write bank = (16*lkg + lrow) % 32 -> 2 lanes/bank = free.
    float* cw = cs + wv * (64 * 36);
    #pragma unroll
    for (int m = 0; m < 4; ++m)
        #pragma unroll
        for (int n = 0; n < 2; ++n)
            #pragma unroll
            for (int r = 0; r < 4; ++r)
                cw[(m * 16 + lkg * 4 + r) * 36 + n * 16 + lrow] = acc[m][n][r];

    // thread tid reads its own wave's region (rows 64wv..64wv+63) -> only
    // same-wave lgkmcnt ordering required, which the compiler enforces.
    const float* myrow = cs + wv * (64 * 36) + lane * 36;  // 144B-aligned
    float a[32];
    #pragma unroll
    for (int j = 0; j < 8; ++j)               // balanced b128 reads
        *(float4*)&a[4 * j] = *(const float4*)&myrow[4 * j];

    // ---------------- activations + stores ----------------
    const size_t ro = (size_t)idx * NG;

    // pi = softmax(a[0..9])
    float mx = a[0];
    #pragma unroll
    for (int g = 1; g < NG; ++g) mx = fmaxf(mx, a[g]);
    float e[NG], ssum = 0.0f;
    #pragma unroll
    for (int g = 0; g < NG; ++g) { e[g] = __expf(a[g] - mx); ssum += e[g]; }
    float inv = 1.0f / ssum;
    #pragma unroll
    for (int g = 0; g < 5; ++g)
        *(float2*)&out_pi[ro + 2 * g] = make_float2(e[2 * g] * inv,
                                                    e[2 * g + 1] * inv);

    // sigma = clip(leaky(a[10..19]) + 1.1, 1e-6, inf)
    #pragma unroll
    for (int g = 0; g < 5; ++g) {
        float xa = a[10 + 2 * g], xb = a[10 + 2 * g + 1];
        float va = fmaxf((xa >= 0.0f ? xa : 0.01f * xa) + 1.1f, 1e-6f);
        float vb = fmaxf((xb >= 0.0f ? xb : 0.01f * xb) + 1.1f, 1e-6f);
        *(float2*)&out_sg[ro + 2 * g] = make_float2(va, vb);
    }

    // mu = leaky(a[20..29]) + 1.0
    #pragma unroll
    for (int g = 0; g < 5; ++g) {
        float xa = a[20 + 2 * g], xb = a[20 + 2 * g + 1];
        float va = (xa >= 0.0f ? xa : 0.01f * xa) + 1.0f;
        float vb = (xb >= 0.0f ? xb : 0.01f * xb) + 1.0f;
        *(float2*)&out_mu[ro + 2 * g] = make_float2(va, vb);
    }
}

// ---------------------------------------------------------------------------
extern "C" void kernel_launch(void* const* d_in, const int* in_sizes, int n_in,
                              void* d_out, int out_size, void* d_ws, size_t ws_size,
                              hipStream_t stream) {
    const float* pos_l    = (const float*)d_in[0];
    const float* pos_p    = (const float*)d_in[1];
    const float* Interact = (const float*)d_in[2];
    const int*   mask     = (const int*)  d_in[3];
    const float* Wpi      = (const float*)d_in[4];
    const float* bpi      = (const float*)d_in[5];
    const float* Wsg      = (const float*)d_in[6];
    const float* bsg      = (const float*)d_in[7];
    const float* Wmu      = (const float*)d_in[8];
    const float* bmu      = (const float*)d_in[9];

    float* out      = (float*)d_out;
    float* out_pi   = out + OFF_PI;
    float* out_sg   = out + OFF_SIGMA;
    float* out_mu   = out + OFF_MU;
    float* out_dist = out + OFF_DIST;
    float* out_mask = out + OFF_MASK;

    hipLaunchKernelGGL(k_fused, dim3(ROWS / 256), dim3(256), 0, stream,
                       pos_l, pos_p, mask, Interact,
                       Wpi, bpi, Wsg, bsg, Wmu, bmu,
                       out_pi, out_sg, out_mu, out_dist, out_mask);
}